// Round 9
// baseline (30584.711 us; speedup 1.0000x reference)
//
#include <hip/hip_runtime.h>

#define B_SZ 2048
#define FEAT 840
#define HID  256
#define LAT  128
#define NQ   12
#define NEMB 512

#define T_SUB 40
#define HSTR  43    // h1 tile stride (T_SUB+2, +1 pad, odd)
#define H2STR 41    // h2 stride; h2 aliased into h1s region

// numpy pairwise 8-accumulator combine: ((r0+r1)+(r2+r3))+((r4+r5)+(r6+r7))
__device__ __forceinline__ float np8_combine(const float* r) {
    float sA = __fadd_rn(r[0], r[1]);
    float sB = __fadd_rn(r[2], r[3]);
    float sC = __fadd_rn(r[4], r[5]);
    float sD = __fadd_rn(r[6], r[7]);
    return __fadd_rn(__fadd_rn(sA, sB), __fadd_rn(sC, sD));
}

// ---------------- w2 repack, j-major: w2r[c2][ly][j*3+k] ----------------
__global__ __launch_bounds__(256) void w2r_kernel(const float* __restrict__ w2,
                                                  float* __restrict__ w2r)
{
    int p = blockIdx.x * 256 + threadIdx.x;          // [0, 256*384)
    if (p >= HID * 384) return;
    int c2 = p / 384, r = p - c2 * 384;
    int ly = r / 12, jk = r - ly * 12;
    int j = jk / 3, k = jk - j * 3;
    w2r[p] = w2[(size_t)(ly*4 + j)*768 + c2*3 + k];
}

// 60 scalar FMAs for one c2 step: weights (A0,A1,A2) float4s, h H0..H6.
// j0:(A0.x,A0.y,A0.z) j1:(A0.w,A1.x,A1.y) j2:(A1.z,A1.w,A2.x) j3:(A2.y,A2.z,A2.w)
#define CSTEP(A0, A1, A2, H0, H1, H2, H3, H4, H5, H6)                  \
    {                                                                  \
        sk[0][0][0] = __fmaf_rn(A0.x, H0, sk[0][0][0]);                \
        sk[0][0][1] = __fmaf_rn(A0.y, H1, sk[0][0][1]);                \
        sk[0][0][2] = __fmaf_rn(A0.z, H2, sk[0][0][2]);                \
        sk[0][1][0] = __fmaf_rn(A0.x, H1, sk[0][1][0]);                \
        sk[0][1][1] = __fmaf_rn(A0.y, H2, sk[0][1][1]);                \
        sk[0][1][2] = __fmaf_rn(A0.z, H3, sk[0][1][2]);                \
        sk[0][2][0] = __fmaf_rn(A0.x, H2, sk[0][2][0]);                \
        sk[0][2][1] = __fmaf_rn(A0.y, H3, sk[0][2][1]);                \
        sk[0][2][2] = __fmaf_rn(A0.z, H4, sk[0][2][2]);                \
        sk[0][3][0] = __fmaf_rn(A0.x, H3, sk[0][3][0]);                \
        sk[0][3][1] = __fmaf_rn(A0.y, H4, sk[0][3][1]);                \
        sk[0][3][2] = __fmaf_rn(A0.z, H5, sk[0][3][2]);                \
        sk[0][4][0] = __fmaf_rn(A0.x, H4, sk[0][4][0]);                \
        sk[0][4][1] = __fmaf_rn(A0.y, H5, sk[0][4][1]);                \
        sk[0][4][2] = __fmaf_rn(A0.z, H6, sk[0][4][2]);                \
        sk[1][0][0] = __fmaf_rn(A0.w, H0, sk[1][0][0]);                \
        sk[1][0][1] = __fmaf_rn(A1.x, H1, sk[1][0][1]);                \
        sk[1][0][2] = __fmaf_rn(A1.y, H2, sk[1][0][2]);                \
        sk[1][1][0] = __fmaf_rn(A0.w, H1, sk[1][1][0]);                \
        sk[1][1][1] = __fmaf_rn(A1.x, H2, sk[1][1][1]);                \
        sk[1][1][2] = __fmaf_rn(A1.y, H3, sk[1][1][2]);                \
        sk[1][2][0] = __fmaf_rn(A0.w, H2, sk[1][2][0]);                \
        sk[1][2][1] = __fmaf_rn(A1.x, H3, sk[1][2][1]);                \
        sk[1][2][2] = __fmaf_rn(A1.y, H4, sk[1][2][2]);                \
        sk[1][3][0] = __fmaf_rn(A0.w, H3, sk[1][3][0]);                \
        sk[1][3][1] = __fmaf_rn(A1.x, H4, sk[1][3][1]);                \
        sk[1][3][2] = __fmaf_rn(A1.y, H5, sk[1][3][2]);                \
        sk[1][4][0] = __fmaf_rn(A0.w, H4, sk[1][4][0]);                \
        sk[1][4][1] = __fmaf_rn(A1.x, H5, sk[1][4][1]);                \
        sk[1][4][2] = __fmaf_rn(A1.y, H6, sk[1][4][2]);                \
        sk[2][0][0] = __fmaf_rn(A1.z, H0, sk[2][0][0]);                \
        sk[2][0][1] = __fmaf_rn(A1.w, H1, sk[2][0][1]);                \
        sk[2][0][2] = __fmaf_rn(A2.x, H2, sk[2][0][2]);                \
        sk[2][1][0] = __fmaf_rn(A1.z, H1, sk[2][1][0]);                \
        sk[2][1][1] = __fmaf_rn(A1.w, H2, sk[2][1][1]);                \
        sk[2][1][2] = __fmaf_rn(A2.x, H3, sk[2][1][2]);                \
        sk[2][2][0] = __fmaf_rn(A1.z, H2, sk[2][2][0]);                \
        sk[2][2][1] = __fmaf_rn(A1.w, H3, sk[2][2][1]);                \
        sk[2][2][2] = __fmaf_rn(A2.x, H4, sk[2][2][2]);                \
        sk[2][3][0] = __fmaf_rn(A1.z, H3, sk[2][3][0]);                \
        sk[2][3][1] = __fmaf_rn(A1.w, H4, sk[2][3][1]);                \
        sk[2][3][2] = __fmaf_rn(A2.x, H5, sk[2][3][2]);                \
        sk[2][4][0] = __fmaf_rn(A1.z, H4, sk[2][4][0]);                \
        sk[2][4][1] = __fmaf_rn(A1.w, H5, sk[2][4][1]);                \
        sk[2][4][2] = __fmaf_rn(A2.x, H6, sk[2][4][2]);                \
        sk[3][0][0] = __fmaf_rn(A2.y, H0, sk[3][0][0]);                \
        sk[3][0][1] = __fmaf_rn(A2.z, H1, sk[3][0][1]);                \
        sk[3][0][2] = __fmaf_rn(A2.w, H2, sk[3][0][2]);                \
        sk[3][1][0] = __fmaf_rn(A2.y, H1, sk[3][1][0]);                \
        sk[3][1][1] = __fmaf_rn(A2.z, H2, sk[3][1][1]);                \
        sk[3][1][2] = __fmaf_rn(A2.w, H3, sk[3][1][2]);                \
        sk[3][2][0] = __fmaf_rn(A2.y, H2, sk[3][2][0]);                \
        sk[3][2][1] = __fmaf_rn(A2.z, H3, sk[3][2][1]);                \
        sk[3][2][2] = __fmaf_rn(A2.w, H4, sk[3][2][2]);                \
        sk[3][3][0] = __fmaf_rn(A2.y, H3, sk[3][3][0]);                \
        sk[3][3][1] = __fmaf_rn(A2.z, H4, sk[3][3][1]);                \
        sk[3][3][2] = __fmaf_rn(A2.w, H5, sk[3][3][2]);                \
        sk[3][4][0] = __fmaf_rn(A2.y, H4, sk[3][4][0]);                \
        sk[3][4][1] = __fmaf_rn(A2.z, H5, sk[3][4][1]);                \
        sk[3][4][2] = __fmaf_rn(A2.w, H6, sk[3][4][2]);                \
    }

// ---------------- encoder, numpy-f32 bit-faithful ----------------
// one block per batch row; 256 threads = 32 l-groups(4 l) x 8 t-groups(5 t).
template <int USE_WR>
__global__ __launch_bounds__(256, 3) void enc32_kernel(
    const float* __restrict__ x,  const float* __restrict__ w1,
    const float* __restrict__ b1, const float* __restrict__ w2,
    const float* __restrict__ w2r,
    const float* __restrict__ b2, float* __restrict__ zout)
{
    __shared__ float xp[FEAT + 4];        // 3376 B
    __shared__ float h1s[HID * HSTR];     // 44032 B; h2 tile aliased here
    __shared__ float leafs[LAT * 8];      // 4096 B        => 51.5 KB total

    const int tid = threadIdx.x;
    const int b   = blockIdx.x;
    const int tx  = tid & 7;        // t-group (5 t's)
    const int ly  = tid >> 3;       // l-group (4 l's)
    const int u0  = tx * 5;

    const float wA = w1[tid*3+0], wB = w1[tid*3+1], wC = w1[tid*3+2];
    const float b1c = b1[tid];
    float b2v[4];
#pragma unroll
    for (int j = 0; j < 4; ++j) b2v[j] = b2[ly*4 + j];

    for (int i = tid; i < FEAT + 2; i += 256)
        xp[i] = (i >= 1 && i <= FEAT) ? x[(size_t)b*FEAT + i - 1] : 0.f;

    // numpy pairwise-840 leaf state (threads 0..127, one l each)
    float racc[8];
    int leaf_id = 0, leaf_pos = 0;
#pragma unroll
    for (int j = 0; j < 8; ++j) racc[j] = 0.f;

    __syncthreads();
    for (int t0 = 0; t0 < FEAT; t0 += T_SUB) {
        // ---- phase A: h1[c=tid][tp], f32 exact conv1 ----
        const bool edge = (t0 == 0) | (t0 + T_SUB == FEAT);
        if (edge) {
            for (int tp = 0; tp < T_SUB + 2; ++tp) {
                int tg = t0 - 1 + tp;
                float v = 0.f;
                if (tg >= 0 && tg < FEAT) {
                    float s = __fadd_rn(__fadd_rn(__fmul_rn(wA, xp[tg]),
                                                  __fmul_rn(wB, xp[tg+1])),
                                        __fmul_rn(wC, xp[tg+2]));
                    s = __fadd_rn(s, b1c);
                    v = s > 0.f ? s : 0.f;
                }
                h1s[tid*HSTR + tp] = v;
            }
        } else {
#pragma unroll 2
            for (int tp = 0; tp < T_SUB + 2; ++tp) {
                int tg = t0 - 1 + tp;
                float s = __fadd_rn(__fadd_rn(__fmul_rn(wA, xp[tg]),
                                              __fmul_rn(wB, xp[tg+1])),
                                    __fmul_rn(wC, xp[tg+2]));
                s = __fadd_rn(s, b1c);
                h1s[tid*HSTR + tp] = s > 0.f ? s : 0.f;
            }
        }
        __syncthreads();

        // ---- phase B: conv2, 4l x 5t, c2-pair software pipeline (PF=1 pair) --
        float sk[4][5][3];
#pragma unroll
        for (int j = 0; j < 4; ++j)
#pragma unroll
            for (int i = 0; i < 5; ++i)
#pragma unroll
                for (int k = 0; k < 3; ++k) sk[j][i][k] = 0.f;

        if (USE_WR) {
            const float* __restrict__ wbase = w2r + ly*12;
            const float* __restrict__ hbase = &h1s[u0];

            float4 w0a[2], w0b[2], w0c[2];   // pair slot -> first c2 weights
            float4 w1a[2], w1b[2], w1c[2];   // pair slot -> second c2 weights
            float  ha[2][7], hb[2][7];

            // preload pair 0 into slot 0
            {
                const float4* pa = (const float4*)(wbase);
                const float4* pb = (const float4*)(wbase + 384);
                w0a[0] = pa[0]; w0b[0] = pa[1]; w0c[0] = pa[2];
                w1a[0] = pb[0]; w1b[0] = pb[1]; w1c[0] = pb[2];
#pragma unroll
                for (int m = 0; m < 7; ++m) {
                    ha[0][m] = hbase[m];
                    hb[0][m] = hbase[HSTR + m];
                }
            }

#pragma unroll 2
            for (int p = 0; p < HID/2 - 1; ++p) {
                const int buf = p & 1, nb = buf ^ 1;
                // prefetch pair p+1
                const float* wp = wbase + (size_t)(p + 1) * 768;
                const float4* pa = (const float4*)(wp);
                const float4* pb = (const float4*)(wp + 384);
                w0a[nb] = pa[0]; w0b[nb] = pa[1]; w0c[nb] = pa[2];
                w1a[nb] = pb[0]; w1b[nb] = pb[1]; w1c[nb] = pb[2];
                const float* hn = hbase + (size_t)(p + 1) * 2 * HSTR;
#pragma unroll
                for (int m = 0; m < 7; ++m) {
                    ha[nb][m] = hn[m];
                    hb[nb][m] = hn[HSTR + m];
                }
                // compute pair p (c2 = 2p, then 2p+1; chains stay c2-ascending)
                CSTEP(w0a[buf], w0b[buf], w0c[buf],
                      ha[buf][0], ha[buf][1], ha[buf][2], ha[buf][3],
                      ha[buf][4], ha[buf][5], ha[buf][6])
                CSTEP(w1a[buf], w1b[buf], w1c[buf],
                      hb[buf][0], hb[buf][1], hb[buf][2], hb[buf][3],
                      hb[buf][4], hb[buf][5], hb[buf][6])
            }
            {   // final pair (slot (HID/2-1)&1 = 1)
                CSTEP(w0a[1], w0b[1], w0c[1],
                      ha[1][0], ha[1][1], ha[1][2], ha[1][3],
                      ha[1][4], ha[1][5], ha[1][6])
                CSTEP(w1a[1], w1b[1], w1c[1],
                      hb[1][0], hb[1][1], hb[1][2], hb[1][3],
                      hb[1][4], hb[1][5], hb[1][6])
            }
        } else {
            const float* __restrict__ wp = w2 + (size_t)(ly*4)*768;
            for (int c2 = 0; c2 < HID; ++c2) {
                const float* hp = &h1s[c2*HSTR + u0];
                float hv[7];
#pragma unroll
                for (int m = 0; m < 7; ++m) hv[m] = hp[m];
#pragma unroll
                for (int j = 0; j < 4; ++j) {
                    float wa = wp[j*768 + c2*3 + 0];
                    float wb = wp[j*768 + c2*3 + 1];
                    float wc = wp[j*768 + c2*3 + 2];
#pragma unroll
                    for (int i = 0; i < 5; ++i) {
                        sk[j][i][0] = __fmaf_rn(wa, hv[i],   sk[j][i][0]);
                        sk[j][i][1] = __fmaf_rn(wb, hv[i+1], sk[j][i][1]);
                        sk[j][i][2] = __fmaf_rn(wc, hv[i+2], sk[j][i][2]);
                    }
                }
            }
        }
        __syncthreads();   // all h1s reads done before h2 overwrites region

        // h2 = fl(fl(m0+m1)+m2) + b2, relu  -> aliased LDS (h1s region)
#pragma unroll
        for (int j = 0; j < 4; ++j)
#pragma unroll
            for (int i = 0; i < 5; ++i) {
                float hh = __fadd_rn(__fadd_rn(sk[j][i][0], sk[j][i][1]), sk[j][i][2]);
                hh = __fadd_rn(hh, b2v[j]);
                hh = hh > 0.f ? hh : 0.f;
                h1s[(ly*4 + j)*H2STR + u0 + i] = hh;
            }
        __syncthreads();

        // reducer: threads 0..127 ingest T_SUB t's in order into numpy leaves
        if (tid < LAT) {
            for (int tt = 0; tt < T_SUB; ++tt) {
                float v = h1s[tid*H2STR + tt];
                int j = leaf_pos & 7;
                racc[j] = (leaf_pos < 8) ? v : __fadd_rn(racc[j], v);
                ++leaf_pos;
                int llen = (leaf_id == 7) ? 112 : 104;
                if (leaf_pos == llen) {
                    leafs[tid*8 + leaf_id] = np8_combine(racc);
                    ++leaf_id; leaf_pos = 0;
                }
            }
        }
        __syncthreads();   // reducer done before next tile's phase A writes h1s
    }

    // numpy pairwise-840 recombination
    if (tid < LAT) {
        const float* L = &leafs[tid*8];
        float s0 = __fadd_rn(L[0], L[1]);
        float s1 = __fadd_rn(L[2], L[3]);
        float sA = __fadd_rn(s0, s1);
        float s2 = __fadd_rn(L[4], L[5]);
        float s3 = __fadd_rn(L[6], L[7]);
        float sB = __fadd_rn(s2, s3);
        float tot = __fadd_rn(sA, sB);
        zout[(size_t)b*LAT + tid] = __fdiv_rn(tot, 840.0f);
    }
}

// ---------------- RVQ, numpy-f32 bit-faithful ----------------
__global__ __launch_bounds__(256) void rvq32_kernel(
    const float* __restrict__ cb, const float* __restrict__ z,
    float* __restrict__ zqout, float* __restrict__ oidx)
{
    __shared__ float rr[LAT];
    __shared__ float Ash;
    __shared__ float redd[256];
    __shared__ int   rede[256];
    __shared__ float sredd[64];
    __shared__ int   srede[64];
    __shared__ int   beste;
    __shared__ float qv[NQ * LAT];

    const int tid = threadIdx.x;
    const int b   = blockIdx.x;

    if (tid < LAT) rr[tid] = z[(size_t)b*LAT + tid];
    __syncthreads();

    for (int q = 0; q < NQ; ++q) {
        const float* __restrict__ cbq = cb + (size_t)q * NEMB * LAT;

        if (tid == 0) {
            float r8[8];
#pragma unroll
            for (int j = 0; j < 8; ++j) r8[j] = __fmul_rn(rr[j], rr[j]);
            for (int i = 8; i < LAT; i += 8)
#pragma unroll
                for (int j = 0; j < 8; ++j)
                    r8[j] = __fadd_rn(r8[j], __fmul_rn(rr[i+j], rr[i+j]));
            Ash = np8_combine(r8);
        }
        __syncthreads();

        float dmin = 0.f; int emin = 0;
#pragma unroll
        for (int h = 0; h < 2; ++h) {
            int e = 2*tid + h;
            const float* __restrict__ cp = cbq + (size_t)e*LAT;
            float dot = 0.f;
            float c8[8];
#pragma unroll
            for (int j = 0; j < 8; ++j) {
                float c = cp[j];
                c8[j] = __fmul_rn(c, c);
                dot = __fmaf_rn(c, rr[j], dot);
            }
            for (int i = 8; i < LAT; i += 8)
#pragma unroll
                for (int j = 0; j < 8; ++j) {
                    float c = cp[i+j];
                    dot = __fmaf_rn(c, rr[i+j], dot);
                    c8[j] = __fadd_rn(c8[j], __fmul_rn(c, c));
                }
            float cn = np8_combine(c8);
            float G  = __fmul_rn(2.0f, dot);
            float d  = __fadd_rn(__fsub_rn(Ash, G), cn);
            if (h == 0) { dmin = d; emin = e; }
            else if (d < dmin) { dmin = d; emin = e; }
        }
        redd[tid] = dmin; rede[tid] = emin;
        __syncthreads();

        if (tid < 64) {
            float bb = redd[tid*4]; int ee = rede[tid*4];
            for (int j = 1; j < 4; ++j) {
                float dj = redd[tid*4 + j];
                if (dj < bb) { bb = dj; ee = rede[tid*4 + j]; }
            }
            sredd[tid] = bb; srede[tid] = ee;
        }
        __syncthreads();
        if (tid == 0) {
            float bb = sredd[0]; int ee = srede[0];
            for (int j = 1; j < 64; ++j) {
                float dj = sredd[j];
                if (dj < bb) { bb = dj; ee = srede[j]; }
            }
            beste = ee;
            oidx[(size_t)b*NQ + q] = (float)ee;
        }
        __syncthreads();

        if (tid < LAT) {
            float cv = cbq[(size_t)beste*LAT + tid];
            qv[q*LAT + tid] = cv;
            rr[tid] = __fsub_rn(rr[tid], cv);
        }
        __syncthreads();
    }

    if (tid < LAT) {
        float s = qv[tid];
        for (int s2 = 1; s2 < NQ; ++s2)
            s = __fadd_rn(s, qv[s2*LAT + tid]);
        zqout[(size_t)b*LAT + tid] = s;
    }
}

extern "C" void kernel_launch(void* const* d_in, const int* in_sizes, int n_in,
                              void* d_out, int out_size, void* d_ws, size_t ws_size,
                              hipStream_t stream)
{
    (void)in_sizes; (void)n_in; (void)out_size;
    const float* x  = (const float*)d_in[0];
    const float* w1 = (const float*)d_in[1];
    const float* b1 = (const float*)d_in[2];
    const float* w2 = (const float*)d_in[3];
    const float* b2 = (const float*)d_in[4];
    const float* cb = (const float*)d_in[5];

    float* out  = (float*)d_out;
    float* zq   = out;                         // 2048*1*128 floats
    float* oidx = out + (size_t)B_SZ * LAT;    // 2048*1*12 floats

    const size_t w2r_bytes = (size_t)HID * 384 * sizeof(float);  // 393216

    if (ws_size >= w2r_bytes) {
        float* w2r = (float*)d_ws;
        w2r_kernel<<<(HID*384 + 255)/256, 256, 0, stream>>>(w2, w2r);
        enc32_kernel<1><<<B_SZ, 256, 0, stream>>>(x, w1, b1, w2, w2r, b2, zq);
    } else {
        enc32_kernel<0><<<B_SZ, 256, 0, stream>>>(x, w1, b1, w2, nullptr, b2, zq);
    }
    rvq32_kernel<<<B_SZ, 256, 0, stream>>>(cb, zq, zq, oidx);
}

// Round 10
// 6179.908 us; speedup vs baseline: 4.9491x; 4.9491x over previous
//
#include <hip/hip_runtime.h>

#define B_SZ 2048
#define FEAT 840
#define HID  256
#define LAT  128
#define NQ   12
#define NEMB 512

#define T_SUB 40
#define HSTR  43    // h1 tile stride (T_SUB+2, +1 pad, odd)
#define H2STR 41    // h2 stride; h2 aliased into h1s region

// numpy pairwise 8-accumulator combine: ((r0+r1)+(r2+r3))+((r4+r5)+(r6+r7))
__device__ __forceinline__ float np8_combine(const float* r) {
    float sA = __fadd_rn(r[0], r[1]);
    float sB = __fadd_rn(r[2], r[3]);
    float sC = __fadd_rn(r[4], r[5]);
    float sD = __fadd_rn(r[6], r[7]);
    return __fadd_rn(__fadd_rn(sA, sB), __fadd_rn(sC, sD));
}

// ---------------- w2 repack, j-major: w2r[c2][ly][j*3+k] ----------------
__global__ __launch_bounds__(256) void w2r_kernel(const float* __restrict__ w2,
                                                  float* __restrict__ w2r)
{
    int p = blockIdx.x * 256 + threadIdx.x;          // [0, 256*384)
    if (p >= HID * 384) return;
    int c2 = p / 384, r = p - c2 * 384;
    int ly = r / 12, jk = r - ly * 12;
    int j = jk / 3, k = jk - j * 3;
    w2r[p] = w2[(size_t)(ly*4 + j)*768 + c2*3 + k];
}

// 60 scalar FMAs for one c2 step: weights (A0,A1,A2) float4s, h H0..H6.
// j0:(A0.x,A0.y,A0.z) j1:(A0.w,A1.x,A1.y) j2:(A1.z,A1.w,A2.x) j3:(A2.y,A2.z,A2.w)
#define CSTEP(A0, A1, A2, H0, H1, H2, H3, H4, H5, H6)                  \
    {                                                                  \
        sk[0][0][0] = __fmaf_rn(A0.x, H0, sk[0][0][0]);                \
        sk[0][0][1] = __fmaf_rn(A0.y, H1, sk[0][0][1]);                \
        sk[0][0][2] = __fmaf_rn(A0.z, H2, sk[0][0][2]);                \
        sk[0][1][0] = __fmaf_rn(A0.x, H1, sk[0][1][0]);                \
        sk[0][1][1] = __fmaf_rn(A0.y, H2, sk[0][1][1]);                \
        sk[0][1][2] = __fmaf_rn(A0.z, H3, sk[0][1][2]);                \
        sk[0][2][0] = __fmaf_rn(A0.x, H2, sk[0][2][0]);                \
        sk[0][2][1] = __fmaf_rn(A0.y, H3, sk[0][2][1]);                \
        sk[0][2][2] = __fmaf_rn(A0.z, H4, sk[0][2][2]);                \
        sk[0][3][0] = __fmaf_rn(A0.x, H3, sk[0][3][0]);                \
        sk[0][3][1] = __fmaf_rn(A0.y, H4, sk[0][3][1]);                \
        sk[0][3][2] = __fmaf_rn(A0.z, H5, sk[0][3][2]);                \
        sk[0][4][0] = __fmaf_rn(A0.x, H4, sk[0][4][0]);                \
        sk[0][4][1] = __fmaf_rn(A0.y, H5, sk[0][4][1]);                \
        sk[0][4][2] = __fmaf_rn(A0.z, H6, sk[0][4][2]);                \
        sk[1][0][0] = __fmaf_rn(A0.w, H0, sk[1][0][0]);                \
        sk[1][0][1] = __fmaf_rn(A1.x, H1, sk[1][0][1]);                \
        sk[1][0][2] = __fmaf_rn(A1.y, H2, sk[1][0][2]);                \
        sk[1][1][0] = __fmaf_rn(A0.w, H1, sk[1][1][0]);                \
        sk[1][1][1] = __fmaf_rn(A1.x, H2, sk[1][1][1]);                \
        sk[1][1][2] = __fmaf_rn(A1.y, H3, sk[1][1][2]);                \
        sk[1][2][0] = __fmaf_rn(A0.w, H2, sk[1][2][0]);                \
        sk[1][2][1] = __fmaf_rn(A1.x, H3, sk[1][2][1]);                \
        sk[1][2][2] = __fmaf_rn(A1.y, H4, sk[1][2][2]);                \
        sk[1][3][0] = __fmaf_rn(A0.w, H3, sk[1][3][0]);                \
        sk[1][3][1] = __fmaf_rn(A1.x, H4, sk[1][3][1]);                \
        sk[1][3][2] = __fmaf_rn(A1.y, H5, sk[1][3][2]);                \
        sk[1][4][0] = __fmaf_rn(A0.w, H4, sk[1][4][0]);                \
        sk[1][4][1] = __fmaf_rn(A1.x, H5, sk[1][4][1]);                \
        sk[1][4][2] = __fmaf_rn(A1.y, H6, sk[1][4][2]);                \
        sk[2][0][0] = __fmaf_rn(A1.z, H0, sk[2][0][0]);                \
        sk[2][0][1] = __fmaf_rn(A1.w, H1, sk[2][0][1]);                \
        sk[2][0][2] = __fmaf_rn(A2.x, H2, sk[2][0][2]);                \
        sk[2][1][0] = __fmaf_rn(A1.z, H1, sk[2][1][0]);                \
        sk[2][1][1] = __fmaf_rn(A1.w, H2, sk[2][1][1]);                \
        sk[2][1][2] = __fmaf_rn(A2.x, H3, sk[2][1][2]);                \
        sk[2][2][0] = __fmaf_rn(A1.z, H2, sk[2][2][0]);                \
        sk[2][2][1] = __fmaf_rn(A1.w, H3, sk[2][2][1]);                \
        sk[2][2][2] = __fmaf_rn(A2.x, H4, sk[2][2][2]);                \
        sk[2][3][0] = __fmaf_rn(A1.z, H3, sk[2][3][0]);                \
        sk[2][3][1] = __fmaf_rn(A1.w, H4, sk[2][3][1]);                \
        sk[2][3][2] = __fmaf_rn(A2.x, H5, sk[2][3][2]);                \
        sk[2][4][0] = __fmaf_rn(A1.z, H4, sk[2][4][0]);                \
        sk[2][4][1] = __fmaf_rn(A1.w, H5, sk[2][4][1]);                \
        sk[2][4][2] = __fmaf_rn(A2.x, H6, sk[2][4][2]);                \
        sk[3][0][0] = __fmaf_rn(A2.y, H0, sk[3][0][0]);                \
        sk[3][0][1] = __fmaf_rn(A2.z, H1, sk[3][0][1]);                \
        sk[3][0][2] = __fmaf_rn(A2.w, H2, sk[3][0][2]);                \
        sk[3][1][0] = __fmaf_rn(A2.y, H1, sk[3][1][0]);                \
        sk[3][1][1] = __fmaf_rn(A2.z, H2, sk[3][1][1]);                \
        sk[3][1][2] = __fmaf_rn(A2.w, H3, sk[3][1][2]);                \
        sk[3][2][0] = __fmaf_rn(A2.y, H2, sk[3][2][0]);                \
        sk[3][2][1] = __fmaf_rn(A2.z, H3, sk[3][2][1]);                \
        sk[3][2][2] = __fmaf_rn(A2.w, H4, sk[3][2][2]);                \
        sk[3][3][0] = __fmaf_rn(A2.y, H3, sk[3][3][0]);                \
        sk[3][3][1] = __fmaf_rn(A2.z, H4, sk[3][3][1]);                \
        sk[3][3][2] = __fmaf_rn(A2.w, H5, sk[3][3][2]);                \
        sk[3][4][0] = __fmaf_rn(A2.y, H4, sk[3][4][0]);                \
        sk[3][4][1] = __fmaf_rn(A2.z, H5, sk[3][4][1]);                \
        sk[3][4][2] = __fmaf_rn(A2.w, H6, sk[3][4][2]);                \
    }

// ---------------- encoder, numpy-f32 bit-faithful ----------------
// one block per batch row; 256 threads = 32 l-groups(4 l) x 8 t-groups(5 t).
template <int USE_WR>
__global__ __launch_bounds__(256) void enc32_kernel(
    const float* __restrict__ x,  const float* __restrict__ w1,
    const float* __restrict__ b1, const float* __restrict__ w2,
    const float* __restrict__ w2r,
    const float* __restrict__ b2, float* __restrict__ zout)
{
    __shared__ float xp[FEAT + 4];        // 3376 B
    __shared__ float h1s[HID * HSTR];     // 44032 B; h2 tile aliased here
    __shared__ float leafs[LAT * 8];      // 4096 B        => 51.5 KB total

    const int tid = threadIdx.x;
    const int b   = blockIdx.x;
    const int tx  = tid & 7;        // t-group (5 t's)
    const int ly  = tid >> 3;       // l-group (4 l's)
    const int u0  = tx * 5;

    const float wA = w1[tid*3+0], wB = w1[tid*3+1], wC = w1[tid*3+2];
    const float b1c = b1[tid];
    float b2v[4];
#pragma unroll
    for (int j = 0; j < 4; ++j) b2v[j] = b2[ly*4 + j];

    for (int i = tid; i < FEAT + 2; i += 256)
        xp[i] = (i >= 1 && i <= FEAT) ? x[(size_t)b*FEAT + i - 1] : 0.f;

    // numpy pairwise-840 leaf state (threads 0..127, one l each)
    float racc[8];
    int leaf_id = 0, leaf_pos = 0;
#pragma unroll
    for (int j = 0; j < 8; ++j) racc[j] = 0.f;

    __syncthreads();
    for (int t0 = 0; t0 < FEAT; t0 += T_SUB) {
        // ---- phase A: h1[c=tid][tp], f32 exact conv1 ----
        const bool edge = (t0 == 0) | (t0 + T_SUB == FEAT);
        if (edge) {
            for (int tp = 0; tp < T_SUB + 2; ++tp) {
                int tg = t0 - 1 + tp;
                float v = 0.f;
                if (tg >= 0 && tg < FEAT) {
                    float s = __fadd_rn(__fadd_rn(__fmul_rn(wA, xp[tg]),
                                                  __fmul_rn(wB, xp[tg+1])),
                                        __fmul_rn(wC, xp[tg+2]));
                    s = __fadd_rn(s, b1c);
                    v = s > 0.f ? s : 0.f;
                }
                h1s[tid*HSTR + tp] = v;
            }
        } else {
#pragma unroll 2
            for (int tp = 0; tp < T_SUB + 2; ++tp) {
                int tg = t0 - 1 + tp;
                float s = __fadd_rn(__fadd_rn(__fmul_rn(wA, xp[tg]),
                                              __fmul_rn(wB, xp[tg+1])),
                                    __fmul_rn(wC, xp[tg+2]));
                s = __fadd_rn(s, b1c);
                h1s[tid*HSTR + tp] = s > 0.f ? s : 0.f;
            }
        }
        __syncthreads();

        // ---- phase B: conv2, 4l x 5t per thread, c2-pair pipeline ----
        float sk[4][5][3];
#pragma unroll
        for (int j = 0; j < 4; ++j)
#pragma unroll
            for (int i = 0; i < 5; ++i)
#pragma unroll
                for (int k = 0; k < 3; ++k) sk[j][i][k] = 0.f;

        if (USE_WR) {
            const float* __restrict__ wbase = w2r + ly*12;
            const float* __restrict__ hbase = &h1s[u0];

            // current pair: explicit named registers only (no arrays!)
            float4 cA0, cA1, cA2, cB0, cB1, cB2;
            float  hA0, hA1, hA2, hA3, hA4, hA5, hA6;
            float  hB0, hB1, hB2, hB3, hB4, hB5, hB6;

            {   // preload pair 0 (c2 = 0, 1)
                const float4* pa = (const float4*)(wbase);
                const float4* pb = (const float4*)(wbase + 384);
                cA0 = pa[0]; cA1 = pa[1]; cA2 = pa[2];
                cB0 = pb[0]; cB1 = pb[1]; cB2 = pb[2];
                hA0 = hbase[0]; hA1 = hbase[1]; hA2 = hbase[2];
                hA3 = hbase[3]; hA4 = hbase[4]; hA5 = hbase[5]; hA6 = hbase[6];
                const float* hbB = hbase + HSTR;
                hB0 = hbB[0]; hB1 = hbB[1]; hB2 = hbB[2];
                hB3 = hbB[3]; hB4 = hbB[4]; hB5 = hbB[5]; hB6 = hbB[6];
            }

#pragma unroll 2
            for (int p = 0; p < HID/2 - 1; ++p) {
                // prefetch pair p+1 (issued before the FMA block)
                const float* wn = wbase + (size_t)(p + 1) * 768;
                const float4* pa = (const float4*)(wn);
                const float4* pb = (const float4*)(wn + 384);
                float4 nA0 = pa[0], nA1 = pa[1], nA2 = pa[2];
                float4 nB0 = pb[0], nB1 = pb[1], nB2 = pb[2];
                const float* hn = hbase + (size_t)(p + 1) * 2 * HSTR;
                float nhA0 = hn[0], nhA1 = hn[1], nhA2 = hn[2], nhA3 = hn[3],
                      nhA4 = hn[4], nhA5 = hn[5], nhA6 = hn[6];
                const float* hnB = hn + HSTR;
                float nhB0 = hnB[0], nhB1 = hnB[1], nhB2 = hnB[2], nhB3 = hnB[3],
                      nhB4 = hnB[4], nhB5 = hnB[5], nhB6 = hnB[6];

                // compute pair p (c2 = 2p then 2p+1; chains stay c2-ascending)
                CSTEP(cA0, cA1, cA2, hA0, hA1, hA2, hA3, hA4, hA5, hA6)
                CSTEP(cB0, cB1, cB2, hB0, hB1, hB2, hB3, hB4, hB5, hB6)

                // rotate (SSA renaming, no movs after unroll)
                cA0 = nA0; cA1 = nA1; cA2 = nA2;
                cB0 = nB0; cB1 = nB1; cB2 = nB2;
                hA0 = nhA0; hA1 = nhA1; hA2 = nhA2; hA3 = nhA3;
                hA4 = nhA4; hA5 = nhA5; hA6 = nhA6;
                hB0 = nhB0; hB1 = nhB1; hB2 = nhB2; hB3 = nhB3;
                hB4 = nhB4; hB5 = nhB5; hB6 = nhB6;
            }
            // final pair (c2 = 254, 255)
            CSTEP(cA0, cA1, cA2, hA0, hA1, hA2, hA3, hA4, hA5, hA6)
            CSTEP(cB0, cB1, cB2, hB0, hB1, hB2, hB3, hB4, hB5, hB6)
        } else {
            const float* __restrict__ wp = w2 + (size_t)(ly*4)*768;
            for (int c2 = 0; c2 < HID; ++c2) {
                const float* hp = &h1s[c2*HSTR + u0];
                float hv[7];
#pragma unroll
                for (int m = 0; m < 7; ++m) hv[m] = hp[m];
#pragma unroll
                for (int j = 0; j < 4; ++j) {
                    float wa = wp[j*768 + c2*3 + 0];
                    float wb = wp[j*768 + c2*3 + 1];
                    float wc = wp[j*768 + c2*3 + 2];
#pragma unroll
                    for (int i = 0; i < 5; ++i) {
                        sk[j][i][0] = __fmaf_rn(wa, hv[i],   sk[j][i][0]);
                        sk[j][i][1] = __fmaf_rn(wb, hv[i+1], sk[j][i][1]);
                        sk[j][i][2] = __fmaf_rn(wc, hv[i+2], sk[j][i][2]);
                    }
                }
            }
        }
        __syncthreads();   // all h1s reads done before h2 overwrites region

        // h2 = fl(fl(m0+m1)+m2) + b2, relu  -> aliased LDS (h1s region)
#pragma unroll
        for (int j = 0; j < 4; ++j)
#pragma unroll
            for (int i = 0; i < 5; ++i) {
                float hh = __fadd_rn(__fadd_rn(sk[j][i][0], sk[j][i][1]), sk[j][i][2]);
                hh = __fadd_rn(hh, b2v[j]);
                hh = hh > 0.f ? hh : 0.f;
                h1s[(ly*4 + j)*H2STR + u0 + i] = hh;
            }
        __syncthreads();

        // reducer: threads 0..127 ingest T_SUB t's in order into numpy leaves
        if (tid < LAT) {
            for (int tt = 0; tt < T_SUB; ++tt) {
                float v = h1s[tid*H2STR + tt];
                int j = leaf_pos & 7;
                racc[j] = (leaf_pos < 8) ? v : __fadd_rn(racc[j], v);
                ++leaf_pos;
                int llen = (leaf_id == 7) ? 112 : 104;
                if (leaf_pos == llen) {
                    leafs[tid*8 + leaf_id] = np8_combine(racc);
                    ++leaf_id; leaf_pos = 0;
                }
            }
        }
        __syncthreads();   // reducer done before next tile's phase A writes h1s
    }

    // numpy pairwise-840 recombination
    if (tid < LAT) {
        const float* L = &leafs[tid*8];
        float s0 = __fadd_rn(L[0], L[1]);
        float s1 = __fadd_rn(L[2], L[3]);
        float sA = __fadd_rn(s0, s1);
        float s2 = __fadd_rn(L[4], L[5]);
        float s3 = __fadd_rn(L[6], L[7]);
        float sB = __fadd_rn(s2, s3);
        float tot = __fadd_rn(sA, sB);
        zout[(size_t)b*LAT + tid] = __fdiv_rn(tot, 840.0f);
    }
}

// ---------------- RVQ, numpy-f32 bit-faithful ----------------
__global__ __launch_bounds__(256) void rvq32_kernel(
    const float* __restrict__ cb, const float* __restrict__ z,
    float* __restrict__ zqout, float* __restrict__ oidx)
{
    __shared__ float rr[LAT];
    __shared__ float Ash;
    __shared__ float redd[256];
    __shared__ int   rede[256];
    __shared__ float sredd[64];
    __shared__ int   srede[64];
    __shared__ int   beste;
    __shared__ float qv[NQ * LAT];

    const int tid = threadIdx.x;
    const int b   = blockIdx.x;

    if (tid < LAT) rr[tid] = z[(size_t)b*LAT + tid];
    __syncthreads();

    for (int q = 0; q < NQ; ++q) {
        const float* __restrict__ cbq = cb + (size_t)q * NEMB * LAT;

        if (tid == 0) {
            float r8[8];
#pragma unroll
            for (int j = 0; j < 8; ++j) r8[j] = __fmul_rn(rr[j], rr[j]);
            for (int i = 8; i < LAT; i += 8)
#pragma unroll
                for (int j = 0; j < 8; ++j)
                    r8[j] = __fadd_rn(r8[j], __fmul_rn(rr[i+j], rr[i+j]));
            Ash = np8_combine(r8);
        }
        __syncthreads();

        float dmin = 0.f; int emin = 0;
#pragma unroll
        for (int h = 0; h < 2; ++h) {
            int e = 2*tid + h;
            const float* __restrict__ cp = cbq + (size_t)e*LAT;
            float dot = 0.f;
            float c8[8];
#pragma unroll
            for (int j = 0; j < 8; ++j) {
                float c = cp[j];
                c8[j] = __fmul_rn(c, c);
                dot = __fmaf_rn(c, rr[j], dot);
            }
            for (int i = 8; i < LAT; i += 8)
#pragma unroll
                for (int j = 0; j < 8; ++j) {
                    float c = cp[i+j];
                    dot = __fmaf_rn(c, rr[i+j], dot);
                    c8[j] = __fadd_rn(c8[j], __fmul_rn(c, c));
                }
            float cn = np8_combine(c8);
            float G  = __fmul_rn(2.0f, dot);
            float d  = __fadd_rn(__fsub_rn(Ash, G), cn);
            if (h == 0) { dmin = d; emin = e; }
            else if (d < dmin) { dmin = d; emin = e; }
        }
        redd[tid] = dmin; rede[tid] = emin;
        __syncthreads();

        if (tid < 64) {
            float bb = redd[tid*4]; int ee = rede[tid*4];
            for (int j = 1; j < 4; ++j) {
                float dj = redd[tid*4 + j];
                if (dj < bb) { bb = dj; ee = rede[tid*4 + j]; }
            }
            sredd[tid] = bb; srede[tid] = ee;
        }
        __syncthreads();
        if (tid == 0) {
            float bb = sredd[0]; int ee = srede[0];
            for (int j = 1; j < 64; ++j) {
                float dj = sredd[j];
                if (dj < bb) { bb = dj; ee = srede[j]; }
            }
            beste = ee;
            oidx[(size_t)b*NQ + q] = (float)ee;
        }
        __syncthreads();

        if (tid < LAT) {
            float cv = cbq[(size_t)beste*LAT + tid];
            qv[q*LAT + tid] = cv;
            rr[tid] = __fsub_rn(rr[tid], cv);
        }
        __syncthreads();
    }

    if (tid < LAT) {
        float s = qv[tid];
        for (int s2 = 1; s2 < NQ; ++s2)
            s = __fadd_rn(s, qv[s2*LAT + tid]);
        zqout[(size_t)b*LAT + tid] = s;
    }
}

extern "C" void kernel_launch(void* const* d_in, const int* in_sizes, int n_in,
                              void* d_out, int out_size, void* d_ws, size_t ws_size,
                              hipStream_t stream)
{
    (void)in_sizes; (void)n_in; (void)out_size;
    const float* x  = (const float*)d_in[0];
    const float* w1 = (const float*)d_in[1];
    const float* b1 = (const float*)d_in[2];
    const float* w2 = (const float*)d_in[3];
    const float* b2 = (const float*)d_in[4];
    const float* cb = (const float*)d_in[5];

    float* out  = (float*)d_out;
    float* zq   = out;                         // 2048*1*128 floats
    float* oidx = out + (size_t)B_SZ * LAT;    // 2048*1*12 floats

    const size_t w2r_bytes = (size_t)HID * 384 * sizeof(float);  // 393216

    if (ws_size >= w2r_bytes) {
        float* w2r = (float*)d_ws;
        w2r_kernel<<<(HID*384 + 255)/256, 256, 0, stream>>>(w2, w2r);
        enc32_kernel<1><<<B_SZ, 256, 0, stream>>>(x, w1, b1, w2, w2r, b2, zq);
    } else {
        enc32_kernel<0><<<B_SZ, 256, 0, stream>>>(x, w1, b1, w2, nullptr, b2, zq);
    }
    rvq32_kernel<<<B_SZ, 256, 0, stream>>>(cb, zq, zq, oidx);
}